// Round 20
// baseline (281.377 us; speedup 1.0000x reference)
//
#include <hip/hip_runtime.h>
#include <math.h>

#define NB 512
#define NL 336
#define NC 321
#define NS 28
#define NW 12
#define NH 25
#define NP 8
#define NG 100
#define NT (NS + NP - 1)  // 35 cell steps
#define BSL 16            // batches per wave (1 MFMA column-tile)
#define WPB 4             // independent waves per 256-thread block
#define LOG2E 1.44269504088896340736f
#define N2LOG2E -2.88539008177792681472f

typedef __attribute__((ext_vector_type(8))) _Float16 f16x8;
typedef __attribute__((ext_vector_type(4))) float f32x4;

union F8 { f16x8 v; _Float16 h[8]; };

// q==3 lane carries the extra K-slots: k25=xt, k26=1.0 (A=bias row), k27..31=0
__device__ __forceinline__ void set_q3f(F8& b, bool q3, float xt) {
    b.h[1] = q3 ? (_Float16)xt : b.h[1];
    b.h[2] = q3 ? (_Float16)1.0f : b.h[2];
    b.h[3] = q3 ? (_Float16)0.0f : b.h[3];
    b.h[4] = q3 ? (_Float16)0.0f : b.h[4];
    b.h[5] = q3 ? (_Float16)0.0f : b.h[5];
    b.h[6] = q3 ? (_Float16)0.0f : b.h[6];
    b.h[7] = q3 ? (_Float16)0.0f : b.h[7];
}

// fused LSTM unit tail: gates (exp2 domain) -> new c (in/out), returns h
__device__ __forceinline__ float cell_tail(const f32x4 a, float& cref) {
    const float ei = __builtin_amdgcn_exp2f(-a[0]);
    const float ef = __builtin_amdgcn_exp2f(-a[1]);
    const float eg = __builtin_amdgcn_exp2f(-a[2]);
    const float eo = __builtin_amdgcn_exp2f(-a[3]);
    const float p1f = 1.0f + ef;
    const float pig = (1.0f + ei) * (1.0f + eg);
    const float num = fmaf(cref, pig, (1.0f - eg) * p1f);
    const float cn  = num * __builtin_amdgcn_rcpf(p1f * pig);
    const float et  = __builtin_amdgcn_exp2f(cn * N2LOG2E);
    cref = cn;
    return (1.0f - et) * __builtin_amdgcn_rcpf((1.0f + eo) * (1.0f + et));
}

// ---------------- Stage 1: mean + segment embedding -------------------------
// (s,b,c) output layout: thread c writes consecutive addresses -> coalesced,
// block-private lines (R19: this layout change took stage 1 to its HBM floor).
extern "C" __global__ __launch_bounds__(384)
void k_seg(const float* __restrict__ x, const float* __restrict__ seg,
           float* __restrict__ seg_bc, float* __restrict__ meanw) {
    const int b = blockIdx.x;
    const int c = threadIdx.x;
    if (c >= NC) return;
    float sw[NW];
#pragma unroll
    for (int w = 0; w < NW; ++w) sw[w] = seg[c * NW + w];
    float acc[NS];
    float s0 = 0.0f, s1 = 0.0f, s2 = 0.0f, s3 = 0.0f;
    const float* xb = x + (size_t)b * NL * NC + c;
#pragma unroll
    for (int s = 0; s < NS; ++s) {
        float a = 0.0f;
        float t0 = 0.0f, t1 = 0.0f, t2 = 0.0f, t3 = 0.0f;
#pragma unroll
        for (int w = 0; w < NW; w += 4) {
            const float v0 = xb[(s * NW + w) * NC];
            const float v1 = xb[(s * NW + w + 1) * NC];
            const float v2 = xb[(s * NW + w + 2) * NC];
            const float v3 = xb[(s * NW + w + 3) * NC];
            t0 += v0; t1 += v1; t2 += v2; t3 += v3;
            a = fmaf(v0, sw[w], a);
            a = fmaf(v1, sw[w + 1], a);
            a = fmaf(v2, sw[w + 2], a);
            a = fmaf(v3, sw[w + 3], a);
        }
        s0 += t0; s1 += t1; s2 += t2; s3 += t3;
        acc[s] = a;
    }
    const float mean = ((s0 + s1) + (s2 + s3)) * (1.0f / (float)NL);
    float ssum = 0.0f;
#pragma unroll
    for (int w = 0; w < NW; ++w) ssum += sw[w];
    meanw[b * NC + c] = mean;
#pragma unroll
    for (int s = 0; s < NS; ++s)
        seg_bc[((size_t)s * NB + b) * NC + c] = acc[s] - mean * ssum;
}

// ---------------- Stage 2: f16-MFMA LSTM, zero-LDS recurrence ---------------
// Fused MFMA->tail per mg at (256,4): one live accumulator (vs 3-phase's
// av[8]+e*[8] arrays), split encoder/decoder loops (R18). Per-wave issue
// floor ~1000 cyc/step (56 quarter-rate trans); stall residual proven
// invariant to occupancy/ILP/op-mix (R10,R13,R15,R17).
extern "C" __global__ __launch_bounds__(256, 4)
void k_lstm(const float* __restrict__ seg_bc, const float* __restrict__ W_ih,
            const float* __restrict__ W_hh, const float* __restrict__ b_ih,
            const float* __restrict__ b_hh, const float* __restrict__ Wp,
            const float* __restrict__ bp, float* __restrict__ preds) {
    const int c = blockIdx.y;
    const int wv = threadIdx.x >> 6;
    const int lane = threadIdx.x & 63;
    const int b0 = (blockIdx.x * WPB + wv) * BSL;
    const int bb = lane & 15;         // column (batch) / A-row
    const int q  = lane >> 4;         // k-chunk / C row-quad
    const bool q3 = (q == 3);

    // ---- hoisted A-fragments from global (one-time, L2-resident) ----
    const int qq = bb >> 2, rr = bb & 3;
    const float srow = (rr == 2) ? 2.88539008177792681472f : LOG2E;
    const float* __restrict__ whh = W_hh + (size_t)c * NG * NH;
    const float* __restrict__ wxp = W_ih + (size_t)c * NG;
    const float* __restrict__ bip = b_ih + (size_t)c * NG;
    const float* __restrict__ bhp = b_hh + (size_t)c * NG;
    F8 afr[8];
#pragma unroll 1
    for (int mg = 0; mg < 8; ++mg) {
        const int jj = qq * 8 + mg;
        const int grow = rr * NH + jj;
        F8 f0;
#pragma unroll
        for (int e = 0; e < 8; ++e) {
            const int k = q * 8 + e;
            float v0 = 0.0f;
            if (jj < NH) {
                if (k < NH)         v0 = whh[grow * NH + k] * srow;
                else if (k == 25)   v0 = wxp[grow] * srow;
                else if (k == 26)   v0 = (bip[grow] + bhp[grow]) * srow;
            }
            f0.h[e] = (_Float16)v0;
        }
        afr[mg] = f0;
    }

    float wpl[8];
#pragma unroll
    for (int mg = 0; mg < 8; ++mg) {
        const int j = q * 8 + mg;
        wpl[mg] = (j < NH) ? Wp[(size_t)c * NH + j] : 0.0f;
    }
    const float bpc = bp[c];

    // ---- initial B-fragment: h = 0, xt = seg_in[s=0] ----
    F8 ph;
    {
        const float x0 = seg_bc[((size_t)0 * NB + b0 + bb) * NC + c];
#pragma unroll
        for (int e = 0; e < 8; ++e) ph.h[e] = (_Float16)0.0f;
        set_q3f(ph, q3, x0);
    }

    float cst[8];
#pragma unroll
    for (int mg = 0; mg < 8; ++mg) cst[mg] = 0.0f;

    // ---- encoder loop: t = 0..NS-2, no projection, fused per-mg tail ----
#pragma unroll 1
    for (int t = 0; t < NS - 1; ++t) {
        const float xn = seg_bc[((size_t)(t + 1) * NB + b0 + bb) * NC + c];

        F8 phn;
#pragma unroll
        for (int mg = 0; mg < 8; ++mg) {
            f32x4 z = {0.0f, 0.0f, 0.0f, 0.0f};
            const f32x4 a = __builtin_amdgcn_mfma_f32_16x16x32_f16(afr[mg].v, ph.v, z, 0, 0, 0);
            phn.h[mg] = (_Float16)cell_tail(a, cst[mg]);
        }
        set_q3f(phn, q3, xn);
        ph = phn;
    }

    // ---- decoder loop: t = NS-1..NT-1, projection every step ----
#pragma unroll 1
    for (int t = NS - 1; t < NT; ++t) {
        F8 phn;
        float pp = 0.0f;
#pragma unroll
        for (int mg = 0; mg < 8; ++mg) {
            f32x4 z = {0.0f, 0.0f, 0.0f, 0.0f};
            const f32x4 a = __builtin_amdgcn_mfma_f32_16x16x32_f16(afr[mg].v, ph.v, z, 0, 0, 0);
            const float hn = cell_tail(a, cst[mg]);
            phn.h[mg] = (_Float16)hn;
            pp = fmaf(hn, wpl[mg], pp);
        }

        pp += __shfl_xor(pp, 16);
        pp += __shfl_xor(pp, 32);
        const float ov = pp + bpc;
        if (q == 0)
            preds[((size_t)c * NP + (t - (NS - 1))) * NB + b0 + bb] = ov;

        if (t + 1 < NT) {
            set_q3f(phn, q3, ov);
            ph = phn;
        }
    }
}

// ---------------- Stage 3: expand predictions to output ---------------------
extern "C" __global__ __launch_bounds__(384)
void k_out(const float* __restrict__ preds, const float* __restrict__ seg,
           const float* __restrict__ meanw, float* __restrict__ out) {
    const int b = blockIdx.x;
    const int p = blockIdx.y;
    const int c = threadIdx.x;
    if (c >= NC) return;
    const float pv = preds[((size_t)c * NP + p) * NB + b];
    const float mean = meanw[b * NC + c];
    float* ob = out + ((size_t)b * (NP * NW) + p * NW) * NC + c;
#pragma unroll
    for (int w = 0; w < NW; ++w)
        ob[w * NC] = fmaf(pv, seg[c * NW + w], mean);
}

extern "C" void kernel_launch(void* const* d_in, const int* in_sizes, int n_in,
                              void* d_out, int out_size, void* d_ws, size_t ws_size,
                              hipStream_t stream) {
    const float* x    = (const float*)d_in[0];
    const float* seg  = (const float*)d_in[1];
    const float* W_ih = (const float*)d_in[2];
    const float* W_hh = (const float*)d_in[3];
    const float* b_ih = (const float*)d_in[4];
    const float* b_hh = (const float*)d_in[5];
    const float* Wp   = (const float*)d_in[6];
    const float* bp   = (const float*)d_in[7];
    float* out = (float*)d_out;

    float* seg_bc = (float*)d_ws;                      // 28*512*321 (s,b,c)
    float* meanw  = seg_bc + (size_t)NS * NB * NC;     // 512*321
    float* preds  = meanw + (size_t)NB * NC;           // 321*8*512

    k_seg<<<NB, 384, 0, stream>>>(x, seg, seg_bc, meanw);
    k_lstm<<<dim3(NB / (BSL * WPB), NC), 256, 0, stream>>>(
        seg_bc, W_ih, W_hh, b_ih, b_hh, Wp, bp, preds);
    k_out<<<dim3(NB, NP), 384, 0, stream>>>(preds, seg, meanw, out);
}